// Round 7
// baseline (558.809 us; speedup 1.0000x reference)
//
#include <hip/hip_runtime.h>

typedef unsigned int u32;
typedef unsigned short u16;
typedef __attribute__((ext_vector_type(8))) short bf16x8;
typedef __attribute__((ext_vector_type(4))) float f32x4;
typedef __attribute__((ext_vector_type(4))) u32 u32x4;

// ---- problem constants ----
// B=256, C=1024, S=14, SS=196, C2=15, NCH=512, CAT=1551 (pad->1600), M=50176
#define EPSBN 1e-5f

// async global->LDS, 16B per lane; LDS dest = wave-uniform base + lane*16 (linear in s)
#define GLDS16(gp, lp) __builtin_amdgcn_global_load_lds( \
    (const __attribute__((address_space(1))) u32*)(gp), \
    (__attribute__((address_space(3))) u32*)(lp), 16, 0, 0)

// ---- ws offsets (bytes) ----
#define OFF_ADW    0ull           // 50176*1600*2 = 160,563,200  (Adw bf16, K-padded)
#define OFF_COVT   0ull           // 50176*1024*2 = 102,760,448  (aliases Adw; dead before Adw written)
#define OFF_S      160563200ull   // 256*15*4
#define OFF_WBZ    160578560ull   // 512*1024*2 bf16 conv_w
#define OFF_WBP    161627136ull   // 512*1600*2 bf16 pw1_w padded
#define OFF_STATSZ 163265536ull   // 1024 f32 (sum,sumsq)
#define OFF_STATSO 163269632ull
#define OFF_SCZ    163273728ull
#define OFF_SHZ    163275776ull
#define OFF_SCO    163277824ull
#define OFF_SHO    163279872ull

static __device__ __forceinline__ float bf2f(u16 h){
  u32 u = ((u32)h) << 16; float f; __builtin_memcpy(&f, &u, 4); return f;
}
static __device__ __forceinline__ u16 f2bf(float f){
  u32 u; __builtin_memcpy(&u, &f, 4);
  u = (u + 0x7fffu + ((u >> 16) & 1u)) >> 16;
  return (u16)u;
}

// ---------------- SE block: s[b][15] = sigmoid(relu(g@fc1^T)@fc2^T) ----------------
__global__ __launch_bounds__(64) void se_kernel(const float* __restrict__ y,
    const float* __restrict__ fc1, const float* __restrict__ fc2, float* __restrict__ sse){
  __shared__ float g[15];
  __shared__ float t[2];
  int b = blockIdx.x, l = threadIdx.x;
  for (int c = 0; c < 15; ++c){
    float p = 0.f;
    for (int k = l; k < 196; k += 64) p += y[((size_t)b*15 + c)*196 + k];
    p += __shfl_xor(p, 32); p += __shfl_xor(p, 16); p += __shfl_xor(p, 8);
    p += __shfl_xor(p, 4);  p += __shfl_xor(p, 2);  p += __shfl_xor(p, 1);
    if (l == 0) g[c] = p * (1.f/196.f);
  }
  __syncthreads();
  if (l < 2){
    float a = 0.f;
    for (int c = 0; c < 15; ++c) a += g[c] * fc1[l*15 + c];
    t[l] = fmaxf(a, 0.f);
  }
  __syncthreads();
  if (l < 15){
    float h = t[0]*fc2[l*2] + t[1]*fc2[l*2+1];
    sse[b*15 + l] = 1.f / (1.f + __expf(-h));
  }
}

// ---------------- weights -> bf16 (pw1 K-padded to 1600 with zeros) ----------------
__global__ void wconv_kernel(const float* __restrict__ cw, const float* __restrict__ pw,
                             u16* __restrict__ wbz, u16* __restrict__ wbp){
  u32 stride = gridDim.x * blockDim.x;
  for (u32 i = blockIdx.x*blockDim.x + threadIdx.x; i < 524288u; i += stride)
    wbz[i] = f2bf(cw[i]);
  for (u32 i = blockIdx.x*blockDim.x + threadIdx.x; i < 819200u; i += stride){
    u32 n = i / 1600u, k = i - n*1600u;
    wbp[i] = f2bf(k < 1551u ? pw[(size_t)n*1551 + k] : 0.f);
  }
}

// ---------------- dwconv(x) + row-center + cov via MFMA -> covT[(b*196+ij)*1024+c] bf16 ----
__global__ __launch_bounds__(256,5) void cov_kernel(const float* __restrict__ x,
    const float* __restrict__ dcw, const float* __restrict__ dcb, u16* __restrict__ covT){
  __shared__ __align__(16) float xs[16*200];       // [c][200] f32, 12,800 B; aliased by covL32
  __shared__ __align__(16) u32 xcb[16*132];        // [c][16 rows][8 u32] + pad, 8,448 B
  __shared__ float wls[16][9];
  __shared__ float wlb[16];
  u32* covL32 = (u32*)xs;                          // [8 cpair][210] u32 = 6,720 B <= 12,800

  int tid = threadIdx.x;
  int c0 = blockIdx.x * 16, b = blockIdx.y;

  {
    const float4* xg = (const float4*)(x + ((size_t)b*1024 + c0)*196);
    for (int i = tid; i < 784; i += 256){
      float4 v = xg[i];
      u32 c = (u32)i / 49u, p4 = (u32)i - c*49u;
      *(float4*)&xs[c*200u + p4*4u] = v;
    }
  }
  if (tid < 144) wls[tid/9][tid%9] = dcw[(size_t)(c0 + tid/9)*9 + (tid%9)];
  if (tid < 16) wlb[tid] = dcb[c0 + tid];
  __syncthreads();

  { // conv + row-center + bf16 pack; one thread = one (c, out-row); branch-free edges
    int c = tid >> 4, i = tid & 15;
    u32 q[8];
    #pragma unroll
    for (int j = 0; j < 8; ++j) q[j] = 0u;
    if (i < 14){
      float wr[9];
      #pragma unroll
      for (int qq = 0; qq < 9; ++qq) wr[qq] = wls[c][qq];
      float topm = (i > 0) ? 1.f : 0.f, botm = (i < 13) ? 1.f : 0.f;
      wr[0] *= topm; wr[1] *= topm; wr[2] *= topm;
      wr[6] *= botm; wr[7] *= botm; wr[8] *= botm;
      float bb = wlb[c];
      float rr[3][16];
      #pragma unroll
      for (int d = 0; d < 3; ++d){
        rr[d][0] = 0.f; rr[d][15] = 0.f;
        int rowr = i + d - 1;
        rowr = rowr < 0 ? 0 : (rowr > 13 ? 13 : rowr);
        const float* src = &xs[c*200 + rowr*14];
        #pragma unroll
        for (int j = 0; j < 7; ++j)
          *(float2*)&rr[d][1 + 2*j] = *(const float2*)&src[2*j];
      }
      float ov[14];
      #pragma unroll
      for (int k = 0; k < 14; ++k){
        float a = bb;
        #pragma unroll
        for (int dy = 0; dy < 3; ++dy)
          #pragma unroll
          for (int dx = 0; dx < 3; ++dx)
            a += wr[dy*3+dx] * rr[dy][k + dx];
        ov[k] = a;
      }
      float mean = 0.f;
      #pragma unroll
      for (int k = 0; k < 14; ++k) mean += ov[k];
      mean *= (1.f/14.f);
      #pragma unroll
      for (int j = 0; j < 7; ++j){
        u32 lo = f2bf(ov[2*j]   - mean);
        u32 hi = f2bf(ov[2*j+1] - mean);
        q[j] = lo | (hi << 16);
      }
    }
    u32x4 q0 = {q[0], q[1], q[2], q[3]};
    u32x4 q1 = {q[4], q[5], q[6], q[7]};
    *(u32x4*)&xcb[c*132 + i*8]     = q0;
    *(u32x4*)&xcb[c*132 + i*8 + 4] = q1;
  }
  __syncthreads();

  { // cov = xc * xc^T / 13 ; B-frag == A-frag for 16x16x32; channel-pair-packed u32 out
    int w = tid >> 6, l = tid & 63, lr = l & 15, lq = l >> 4;
    #pragma unroll
    for (int pp = 0; pp < 2; ++pp){
      int clo = w*4 + 2*pp;
      bf16x8 alo = {0,0,0,0,0,0,0,0}, ahi = {0,0,0,0,0,0,0,0};
      if (lq < 2){
        alo = *(const bf16x8*)&xcb[clo*132 + lr*8 + lq*4];
        ahi = *(const bf16x8*)&xcb[(clo+1)*132 + lr*8 + lq*4];
      }
      f32x4 dlo = {0.f,0.f,0.f,0.f}, dhi = {0.f,0.f,0.f,0.f};
      dlo = __builtin_amdgcn_mfma_f32_16x16x32_bf16(alo, alo, dlo, 0, 0, 0);
      dhi = __builtin_amdgcn_mfma_f32_16x16x32_bf16(ahi, ahi, dhi, 0, 0, 0);
      if (lr < 14){
        int cp = w*2 + pp;
        #pragma unroll
        for (int r = 0; r < 4; ++r){
          int rowi = lq*4 + r;   // D: row=(lane>>4)*4+reg, col=lane&15
          if (rowi < 14){
            u32 vv = (u32)f2bf(dlo[r] * (1.f/13.f)) | ((u32)f2bf(dhi[r] * (1.f/13.f)) << 16);
            covL32[cp*210 + rowi*14 + lr] = vv;
          }
        }
      }
    }
  }
  __syncthreads();

  for (int i = tid; i < 1568; i += 256){  // transpose-out: channel-pair u32 per element
    int cp = i & 7, ij = i >> 3;
    u32 v = covL32[cp*210 + ij];
    *(u32*)(covT + ((size_t)(b*196 + ij)*1024 + c0 + 2*cp)) = v;
  }
}

// ---------------- build Adw[(b*196+ij)*1600+cc] = dw3x3(cat)[cc] bf16 ----------------
__global__ __launch_bounds__(256,5) void adw_kernel(
    const float* __restrict__ y, const float* __restrict__ sse,
    const u16* __restrict__ zT, const float* __restrict__ scz, const float* __restrict__ shz,
    const float* __restrict__ x, const float* __restrict__ dw1w, const float* __restrict__ dw1b,
    u16* __restrict__ Adw){
  __shared__ __align__(16) float ms[32*202];       // 25,856 B
  __shared__ float wd[32][9];
  __shared__ float bd[32];
  int tid = threadIdx.x;
  int cc0 = blockIdx.x * 32, b = blockIdx.y;

  for (int i = tid; i < 288; i += 256){
    int c = i / 9, q = i - c*9;
    int cc = cc0 + c;
    wd[c][q] = (cc < 1551) ? dw1w[(size_t)cc*9 + q] : 0.f;
  }
  if (tid < 32) bd[tid] = (cc0 + tid < 1551) ? dw1b[cc0 + tid] : 0.f;

  if (cc0 < 15){                                   // y1 channels [0,15) (chunk 0 only)
    int ny = 15;
    for (int i = tid; i < ny*196; i += 256){
      u32 c = (u32)i / 196u, p = (u32)i - c*196u;
      ms[c*202u + p] = y[((size_t)b*15 + c)*196 + p] * sse[b*15 + c];
    }
  }
  {                                                // z channels [15,527) from zT rows
    int zs = cc0 > 15 ? cc0 : 15;
    int ze = cc0 + 32 < 527 ? cc0 + 32 : 527;
    if (zs < ze){
      int nz = ze - zs, lbase = zs - cc0, obase = zs - 15;
      const u16* zrow = zT + (size_t)obase*50176 + (size_t)b*196;
      for (int i = tid; i < nz*98; i += 256){
        u32 oo = (u32)i / 98u, pp = (u32)i - oo*98u;
        u32 v = *(const u32*)(zrow + (size_t)oo*50176 + pp*2u);
        int o = obase + (int)oo;
        float s = scz[o], h = shz[o];
        float v0 = bf2f((u16)(v & 0xffffu)) * s + h;
        float v1 = bf2f((u16)(v >> 16))     * s + h;
        v0 = 1.f / (1.f + __expf(-v0));
        v1 = 1.f / (1.f + __expf(-v1));
        float2 fv = {v0, v1};
        *(float2*)&ms[(u32)(lbase + (int)oo)*202u + pp*2u] = fv;
      }
    }
  }
  {                                                // x channels [527,1551): float4 loads
    int xs_ = cc0 > 527 ? cc0 : 527;
    int xe = cc0 + 32 < 1551 ? cc0 + 32 : 1551;
    if (xs_ < xe){
      int nx = xe - xs_, lbase = xs_ - cc0, cxs = xs_ - 527;
      const float4* xg = (const float4*)(x + ((size_t)b*1024 + cxs)*196);
      for (int i = tid; i < nx*49; i += 256){
        float4 v = xg[i];
        u32 c = (u32)i / 49u, p4 = (u32)i - c*49u;
        float* dst = &ms[(u32)(lbase + (int)c)*202u + p4*4u];
        float2 lo = {v.x, v.y}, hi = {v.z, v.w};
        *(float2*)dst = lo;
        *(float2*)(dst + 2) = hi;
      }
    }
  }
  {                                                // K pad [1551,1600) -> zeros
    int ps = cc0 > 1551 ? cc0 : 1551;
    int pe = cc0 + 32;
    if (ps < pe){
      int np = pe - ps, lbase = ps - cc0;
      for (int i = tid; i < np*196; i += 256){
        u32 c = (u32)i / 196u, p = (u32)i - c*196u;
        ms[(u32)(lbase + (int)c)*202u + p] = 0.f;
      }
    }
  }
  __syncthreads();

  for (int t = tid; t < 448; t += 256){            // conv: one thread = one (cc, out-row)
    int cc = t & 31, i = t >> 5;
    float wr[9];
    #pragma unroll
    for (int qq = 0; qq < 9; ++qq) wr[qq] = wd[cc][qq];
    float topm = (i > 0) ? 1.f : 0.f, botm = (i < 13) ? 1.f : 0.f;
    wr[0] *= topm; wr[1] *= topm; wr[2] *= topm;
    wr[6] *= botm; wr[7] *= botm; wr[8] *= botm;
    float bb = bd[cc];
    float rr[3][16];
    #pragma unroll
    for (int d = 0; d < 3; ++d){
      rr[d][0] = 0.f; rr[d][15] = 0.f;
      int rowr = i + d - 1;
      rowr = rowr < 0 ? 0 : (rowr > 13 ? 13 : rowr);
      const float* src = &ms[cc*202 + rowr*14];
      #pragma unroll
      for (int j = 0; j < 7; ++j)
        *(float2*)&rr[d][1 + 2*j] = *(const float2*)&src[2*j];
    }
    size_t obase = ((size_t)b*196 + i*14) * 1600 + cc0 + cc;
    #pragma unroll
    for (int k = 0; k < 14; ++k){
      float a = bb;
      #pragma unroll
      for (int dy = 0; dy < 3; ++dy)
        #pragma unroll
        for (int dx = 0; dx < 3; ++dx)
          a += wr[dy*3+dx] * rr[dy][k + dx];
      Adw[obase + (size_t)k*1600] = f2bf(a);
    }
  }
}

// ---------------- NT GEMM v2: BM=64, BN=512 (full N), BK=64, 512 thr / 8 waves ----------
// A read EXACTLY ONCE (no n-block refetch); B (<=1.6MB) stays L2-resident.
// Staging via global_load_lds w16, XOR swizzle folded into source address.
// MODE 0: store bf16 transposed zT[n][m]. MODE 1: store f32 NCHW-transposed (o).
template<int MODE>
__global__ __launch_bounds__(512,4) void gemm_kernel(
    const u16* __restrict__ A, const u16* __restrict__ Bw,
    const float* __restrict__ bias, void* __restrict__ outp,
    float* __restrict__ stats, int K){
  __shared__ __align__(16) char smem[73728];
  u16* As = (u16*)smem;                    // [64][64] bf16, 8 KB
  u16* Bs = (u16*)(smem + 8192);           // [512][64] bf16, 64 KB

  int tid = threadIdx.x;
  int w = tid >> 6, l = tid & 63;
  int lr = l & 15, lq = l >> 4;
  int m0 = blockIdx.x * 64;

  f32x4 acc[4][4] = {};
  int kTiles = K >> 6;

  for (int kt = 0; kt < kTiles; ++kt){
    if (kt) __syncthreads();               // previous tile's readers done
    {
      int s = tid;                         // A: 64 rows x 8 groups
      int row = s >> 3, c8 = s & 7, sc = c8 ^ (row & 7);
      GLDS16(A + (size_t)(m0 + row)*K + kt*64 + sc*8, As + s*8);
    }
    #pragma unroll
    for (int i = 0; i < 8; ++i){           // B: 512 rows x 8 groups
      int s = tid + i*512;
      int row = s >> 3, c8 = s & 7, sc = c8 ^ (row & 7);
      GLDS16(Bw + (size_t)row*K + kt*64 + sc*8, Bs + s*8);
    }
    __syncthreads();                       // drains vmcnt -> LDS tile ready
    #pragma unroll
    for (int ks = 0; ks < 2; ++ks){
      bf16x8 af[4], bfv[4];
      #pragma unroll
      for (int mi = 0; mi < 4; ++mi){
        int row = mi*16 + lr;
        int q = (ks*4 + lq) ^ (row & 7);
        af[mi] = *(const bf16x8*)(As + row*64 + q*8);
      }
      #pragma unroll
      for (int ni = 0; ni < 4; ++ni){
        int row = w*64 + ni*16 + lr;
        int q = (ks*4 + lq) ^ (row & 7);
        bfv[ni] = *(const bf16x8*)(Bs + row*64 + q*8);
      }
      #pragma unroll
      for (int mi = 0; mi < 4; ++mi)
        #pragma unroll
        for (int ni = 0; ni < 4; ++ni)
          acc[mi][ni] = __builtin_amdgcn_mfma_f32_16x16x32_bf16(af[mi], bfv[ni], acc[mi][ni], 0, 0, 0);
    }
  }

  // bias + per-column BN stats (sum, sumsq); this block covers 64 m-rows
  #pragma unroll
  for (int ni = 0; ni < 4; ++ni){
    int col = w*64 + ni*16 + lr;
    float bb = bias[col];
    float s1 = 0.f, s2 = 0.f;
    #pragma unroll
    for (int mi = 0; mi < 4; ++mi)
      #pragma unroll
      for (int r = 0; r < 4; ++r){
        float v = acc[mi][ni][r] + bb;
        acc[mi][ni][r] = v;
        s1 += v; s2 += v*v;
      }
    s1 += __shfl_xor(s1, 16); s1 += __shfl_xor(s1, 32);
    s2 += __shfl_xor(s2, 16); s2 += __shfl_xor(s2, 32);
    if (lq == 0){
      atomicAdd(&stats[col], s1);
      atomicAdd(&stats[512 + col], s2);
    }
  }

  // LDS transpose -> m-contiguous stores; 2 rounds x 4 waves (4 x 64x65 f32 regions)
  __syncthreads();                         // all waves done reading As/Bs
  float* eb = (float*)smem;
  #pragma unroll
  for (int rnd = 0; rnd < 2; ++rnd){
    if ((w >> 2) == rnd){
      float* e = eb + (w & 3) * (64*65);
      #pragma unroll
      for (int mi = 0; mi < 4; ++mi)
        #pragma unroll
        for (int ni = 0; ni < 4; ++ni)
          #pragma unroll
          for (int r = 0; r < 4; ++r)
            e[(mi*16 + lq*4 + r)*65 + ni*16 + lr] = acc[mi][ni][r];
      int m = m0 + l;                      // same-wave readback (DS in-order per wave)
      if (MODE == 0){
        u16* ob = (u16*)outp + (size_t)(w*64)*50176 + m;
        #pragma unroll 8
        for (int no = 0; no < 64; ++no)
          ob[(size_t)no*50176] = f2bf(e[l*65 + no]);
      } else {
        u32 bq = (u32)m / 196u;
        u32 ij = (u32)m - bq*196u;
        float* ob = (float*)outp + ((size_t)bq*512 + w*64)*196 + ij;
        #pragma unroll 8
        for (int no = 0; no < 64; ++no)
          ob[(size_t)no*196] = e[l*65 + no];
      }
    }
    __syncthreads();
  }
}

// ---------------- BN prep: stats -> scale/shift ----------------
__global__ void bnprep_kernel(const float* __restrict__ stats, const float* __restrict__ gamma,
    const float* __restrict__ beta, float* __restrict__ sc, float* __restrict__ sh){
  int o = threadIdx.x;
  float m = stats[o] * (1.f/50176.f);
  float v = stats[512+o] * (1.f/50176.f) - m*m;
  float inv = rsqrtf(v + EPSBN);
  float g = gamma[o] * inv;
  sc[o] = g;
  sh[o] = beta[o] - m*g;
}

// ---------------- final: relu(bn(o)) in place on d_out (NCHW) ----------------
__global__ void final_kernel(float4* __restrict__ o4, const float* __restrict__ sc,
                             const float* __restrict__ sh){
  u32 stride = gridDim.x * blockDim.x;
  for (u32 i = blockIdx.x*blockDim.x + threadIdx.x; i < 6422528u; i += stride){
    u32 oc = (i / 49u) & 511u;
    float s = sc[oc], t = sh[oc];
    float4 v = o4[i];
    v.x = fmaxf(fmaf(v.x, s, t), 0.f);
    v.y = fmaxf(fmaf(v.y, s, t), 0.f);
    v.z = fmaxf(fmaf(v.z, s, t), 0.f);
    v.w = fmaxf(fmaf(v.w, s, t), 0.f);
    o4[i] = v;
  }
}

extern "C" void kernel_launch(void* const* d_in, const int* in_sizes, int n_in,
                              void* d_out, int out_size, void* d_ws, size_t ws_size,
                              hipStream_t stream){
  (void)in_sizes; (void)n_in; (void)out_size; (void)ws_size;
  const float* y      = (const float*)d_in[0];
  const float* x      = (const float*)d_in[1];
  const float* fc1    = (const float*)d_in[2];
  const float* fc2    = (const float*)d_in[3];
  const float* convw  = (const float*)d_in[4];
  const float* convb  = (const float*)d_in[5];
  const float* dconvw = (const float*)d_in[6];
  const float* dconvb = (const float*)d_in[7];
  const float* dw1w   = (const float*)d_in[8];
  const float* dw1b   = (const float*)d_in[9];
  const float* pw1w   = (const float*)d_in[10];
  const float* pw1b   = (const float*)d_in[11];
  const float* gamma  = (const float*)d_in[12];
  const float* beta   = (const float*)d_in[13];

  char* ws = (char*)d_ws;
  u16* covT   = (u16*)(ws + OFF_COVT);
  u16* Adw    = (u16*)(ws + OFF_ADW);
  float* sse  = (float*)(ws + OFF_S);
  u16* wbz    = (u16*)(ws + OFF_WBZ);
  u16* wbp    = (u16*)(ws + OFF_WBP);
  float* statsZ = (float*)(ws + OFF_STATSZ);
  float* statsO = (float*)(ws + OFF_STATSO);
  float* scz  = (float*)(ws + OFF_SCZ);
  float* shz  = (float*)(ws + OFF_SHZ);
  float* sco  = (float*)(ws + OFF_SCO);
  float* sho  = (float*)(ws + OFF_SHO);
  u16* zT     = (u16*)d_out;      // z transposed [512][50176] bf16 in d_out, dead before o written
  float* outf = (float*)d_out;

  hipMemsetAsync(statsZ, 0, 8192, stream);
  se_kernel<<<256, 64, 0, stream>>>(y, fc1, fc2, sse);
  wconv_kernel<<<2048, 256, 0, stream>>>(convw, pw1w, wbz, wbp);
  cov_kernel<<<dim3(64, 256), 256, 0, stream>>>(x, dconvw, dconvb, covT);
  gemm_kernel<0><<<784, 512, 0, stream>>>(covT, wbz, convb, (void*)zT, statsZ, 1024);
  bnprep_kernel<<<1, 512, 0, stream>>>(statsZ, gamma, beta, scz, shz);
  adw_kernel<<<dim3(50, 256), 256, 0, stream>>>(y, sse, zT, scz, shz, x, dw1w, dw1b, Adw);
  gemm_kernel<1><<<784, 512, 0, stream>>>(Adw, wbp, pw1b, (void*)outf, statsO, 1600);
  bnprep_kernel<<<1, 512, 0, stream>>>(statsO, gamma, beta, sco, sho);
  final_kernel<<<8192, 256, 0, stream>>>((float4*)outf, sco, sho);
}

// Round 8
// 516.603 us; speedup vs baseline: 1.0817x; 1.0817x over previous
//
#include <hip/hip_runtime.h>

typedef unsigned int u32;
typedef unsigned short u16;
typedef __attribute__((ext_vector_type(8))) short bf16x8;
typedef __attribute__((ext_vector_type(4))) float f32x4;
typedef __attribute__((ext_vector_type(4))) u32 u32x4;

// ---- problem constants ----
// B=256, C=1024, S=14, SS=196, C2=15, NCH=512, CAT=1551 (pad->1600), M=50176
#define EPSBN 1e-5f

// async global->LDS, 16B per lane; LDS dest = wave-uniform base + lane*16 (linear in s)
#define GLDS16(gp, lp) __builtin_amdgcn_global_load_lds( \
    (const __attribute__((address_space(1))) u32*)(gp), \
    (__attribute__((address_space(3))) u32*)(lp), 16, 0, 0)

// ---- ws offsets (bytes) ----
#define OFF_ADW    0ull           // 50176*1600*2 = 160,563,200  (Adw bf16, K-padded)
#define OFF_COVT   0ull           // 50176*1024*2 = 102,760,448  (aliases Adw; dead before Adw written)
#define OFF_S      160563200ull   // 256*15*4
#define OFF_WBZ    160578560ull   // 512*1024*2 bf16 conv_w
#define OFF_WBP    161627136ull   // 512*1600*2 bf16 pw1_w padded
#define OFF_STATSZ 163265536ull   // 1024 f32 (sum,sumsq)
#define OFF_STATSO 163269632ull
#define OFF_SCZ    163273728ull
#define OFF_SHZ    163275776ull
#define OFF_SCO    163277824ull
#define OFF_SHO    163279872ull

static __device__ __forceinline__ float bf2f(u16 h){
  u32 u = ((u32)h) << 16; float f; __builtin_memcpy(&f, &u, 4); return f;
}
static __device__ __forceinline__ u16 f2bf(float f){
  u32 u; __builtin_memcpy(&u, &f, 4);
  u = (u + 0x7fffu + ((u >> 16) & 1u)) >> 16;
  return (u16)u;
}

// ---------------- SE block: s[b][15] = sigmoid(relu(g@fc1^T)@fc2^T) ----------------
__global__ __launch_bounds__(64) void se_kernel(const float* __restrict__ y,
    const float* __restrict__ fc1, const float* __restrict__ fc2, float* __restrict__ sse){
  __shared__ float g[15];
  __shared__ float t[2];
  int b = blockIdx.x, l = threadIdx.x;
  for (int c = 0; c < 15; ++c){
    float p = 0.f;
    for (int k = l; k < 196; k += 64) p += y[((size_t)b*15 + c)*196 + k];
    p += __shfl_xor(p, 32); p += __shfl_xor(p, 16); p += __shfl_xor(p, 8);
    p += __shfl_xor(p, 4);  p += __shfl_xor(p, 2);  p += __shfl_xor(p, 1);
    if (l == 0) g[c] = p * (1.f/196.f);
  }
  __syncthreads();
  if (l < 2){
    float a = 0.f;
    for (int c = 0; c < 15; ++c) a += g[c] * fc1[l*15 + c];
    t[l] = fmaxf(a, 0.f);
  }
  __syncthreads();
  if (l < 15){
    float h = t[0]*fc2[l*2] + t[1]*fc2[l*2+1];
    sse[b*15 + l] = 1.f / (1.f + __expf(-h));
  }
}

// ---------------- weights -> bf16 (pw1 K-padded to 1600 with zeros) ----------------
__global__ void wconv_kernel(const float* __restrict__ cw, const float* __restrict__ pw,
                             u16* __restrict__ wbz, u16* __restrict__ wbp){
  u32 stride = gridDim.x * blockDim.x;
  for (u32 i = blockIdx.x*blockDim.x + threadIdx.x; i < 524288u; i += stride)
    wbz[i] = f2bf(cw[i]);
  for (u32 i = blockIdx.x*blockDim.x + threadIdx.x; i < 819200u; i += stride){
    u32 n = i / 1600u, k = i - n*1600u;
    wbp[i] = f2bf(k < 1551u ? pw[(size_t)n*1551 + k] : 0.f);
  }
}

// ---------------- dwconv(x) + row-center + cov via MFMA -> covT[(b*196+ij)*1024+c] bf16 ----
__global__ __launch_bounds__(256,5) void cov_kernel(const float* __restrict__ x,
    const float* __restrict__ dcw, const float* __restrict__ dcb, u16* __restrict__ covT){
  __shared__ __align__(16) float xs[16*200];       // [c][200] f32, 12,800 B; aliased by covL32
  __shared__ __align__(16) u32 xcb[16*132];        // [c][16 rows][8 u32] + pad, 8,448 B
  __shared__ float wls[16][9];
  __shared__ float wlb[16];
  u32* covL32 = (u32*)xs;                          // [8 cpair][210] u32 = 6,720 B <= 12,800

  int tid = threadIdx.x;
  int c0 = blockIdx.x * 16, b = blockIdx.y;

  {
    const float4* xg = (const float4*)(x + ((size_t)b*1024 + c0)*196);
    for (int i = tid; i < 784; i += 256){
      float4 v = xg[i];
      u32 c = (u32)i / 49u, p4 = (u32)i - c*49u;
      *(float4*)&xs[c*200u + p4*4u] = v;
    }
  }
  if (tid < 144) wls[tid/9][tid%9] = dcw[(size_t)(c0 + tid/9)*9 + (tid%9)];
  if (tid < 16) wlb[tid] = dcb[c0 + tid];
  __syncthreads();

  { // conv + row-center + bf16 pack; one thread = one (c, out-row); branch-free edges
    int c = tid >> 4, i = tid & 15;
    u32 q[8];
    #pragma unroll
    for (int j = 0; j < 8; ++j) q[j] = 0u;
    if (i < 14){
      float wr[9];
      #pragma unroll
      for (int qq = 0; qq < 9; ++qq) wr[qq] = wls[c][qq];
      float topm = (i > 0) ? 1.f : 0.f, botm = (i < 13) ? 1.f : 0.f;
      wr[0] *= topm; wr[1] *= topm; wr[2] *= topm;
      wr[6] *= botm; wr[7] *= botm; wr[8] *= botm;
      float bb = wlb[c];
      float rr[3][16];
      #pragma unroll
      for (int d = 0; d < 3; ++d){
        rr[d][0] = 0.f; rr[d][15] = 0.f;
        int rowr = i + d - 1;
        rowr = rowr < 0 ? 0 : (rowr > 13 ? 13 : rowr);
        const float* src = &xs[c*200 + rowr*14];
        #pragma unroll
        for (int j = 0; j < 7; ++j)
          *(float2*)&rr[d][1 + 2*j] = *(const float2*)&src[2*j];
      }
      float ov[14];
      #pragma unroll
      for (int k = 0; k < 14; ++k){
        float a = bb;
        #pragma unroll
        for (int dy = 0; dy < 3; ++dy)
          #pragma unroll
          for (int dx = 0; dx < 3; ++dx)
            a += wr[dy*3+dx] * rr[dy][k + dx];
        ov[k] = a;
      }
      float mean = 0.f;
      #pragma unroll
      for (int k = 0; k < 14; ++k) mean += ov[k];
      mean *= (1.f/14.f);
      #pragma unroll
      for (int j = 0; j < 7; ++j){
        u32 lo = f2bf(ov[2*j]   - mean);
        u32 hi = f2bf(ov[2*j+1] - mean);
        q[j] = lo | (hi << 16);
      }
    }
    u32x4 q0 = {q[0], q[1], q[2], q[3]};
    u32x4 q1 = {q[4], q[5], q[6], q[7]};
    *(u32x4*)&xcb[c*132 + i*8]     = q0;
    *(u32x4*)&xcb[c*132 + i*8 + 4] = q1;
  }
  __syncthreads();

  { // cov = xc * xc^T / 13 ; B-frag == A-frag for 16x16x32; channel-pair-packed u32 out
    int w = tid >> 6, l = tid & 63, lr = l & 15, lq = l >> 4;
    #pragma unroll
    for (int pp = 0; pp < 2; ++pp){
      int clo = w*4 + 2*pp;
      bf16x8 alo = {0,0,0,0,0,0,0,0}, ahi = {0,0,0,0,0,0,0,0};
      if (lq < 2){
        alo = *(const bf16x8*)&xcb[clo*132 + lr*8 + lq*4];
        ahi = *(const bf16x8*)&xcb[(clo+1)*132 + lr*8 + lq*4];
      }
      f32x4 dlo = {0.f,0.f,0.f,0.f}, dhi = {0.f,0.f,0.f,0.f};
      dlo = __builtin_amdgcn_mfma_f32_16x16x32_bf16(alo, alo, dlo, 0, 0, 0);
      dhi = __builtin_amdgcn_mfma_f32_16x16x32_bf16(ahi, ahi, dhi, 0, 0, 0);
      if (lr < 14){
        int cp = w*2 + pp;
        #pragma unroll
        for (int r = 0; r < 4; ++r){
          int rowi = lq*4 + r;   // D: row=(lane>>4)*4+reg, col=lane&15
          if (rowi < 14){
            u32 vv = (u32)f2bf(dlo[r] * (1.f/13.f)) | ((u32)f2bf(dhi[r] * (1.f/13.f)) << 16);
            covL32[cp*210 + rowi*14 + lr] = vv;
          }
        }
      }
    }
  }
  __syncthreads();

  for (int i = tid; i < 1568; i += 256){  // transpose-out: channel-pair u32 per element
    int cp = i & 7, ij = i >> 3;
    u32 v = covL32[cp*210 + ij];
    *(u32*)(covT + ((size_t)(b*196 + ij)*1024 + c0 + 2*cp)) = v;
  }
}

// ---------------- build Adw[(b*196+ij)*1600+cc] = dw3x3(cat)[cc] bf16 ----------------
__global__ __launch_bounds__(256,5) void adw_kernel(
    const float* __restrict__ y, const float* __restrict__ sse,
    const u16* __restrict__ zT, const float* __restrict__ scz, const float* __restrict__ shz,
    const float* __restrict__ x, const float* __restrict__ dw1w, const float* __restrict__ dw1b,
    u16* __restrict__ Adw){
  __shared__ __align__(16) float ms[32*202];       // 25,856 B
  __shared__ float wd[32][9];
  __shared__ float bd[32];
  int tid = threadIdx.x;
  int cc0 = blockIdx.x * 32, b = blockIdx.y;

  for (int i = tid; i < 288; i += 256){
    int c = i / 9, q = i - c*9;
    int cc = cc0 + c;
    wd[c][q] = (cc < 1551) ? dw1w[(size_t)cc*9 + q] : 0.f;
  }
  if (tid < 32) bd[tid] = (cc0 + tid < 1551) ? dw1b[cc0 + tid] : 0.f;

  if (cc0 < 15){                                   // y1 channels [0,15) (chunk 0 only)
    int ny = 15;
    for (int i = tid; i < ny*196; i += 256){
      u32 c = (u32)i / 196u, p = (u32)i - c*196u;
      ms[c*202u + p] = y[((size_t)b*15 + c)*196 + p] * sse[b*15 + c];
    }
  }
  {                                                // z channels [15,527) from zT rows
    int zs = cc0 > 15 ? cc0 : 15;
    int ze = cc0 + 32 < 527 ? cc0 + 32 : 527;
    if (zs < ze){
      int nz = ze - zs, lbase = zs - cc0, obase = zs - 15;
      const u16* zrow = zT + (size_t)obase*50176 + (size_t)b*196;
      for (int i = tid; i < nz*98; i += 256){
        u32 oo = (u32)i / 98u, pp = (u32)i - oo*98u;
        u32 v = *(const u32*)(zrow + (size_t)oo*50176 + pp*2u);
        int o = obase + (int)oo;
        float s = scz[o], h = shz[o];
        float v0 = bf2f((u16)(v & 0xffffu)) * s + h;
        float v1 = bf2f((u16)(v >> 16))     * s + h;
        v0 = 1.f / (1.f + __expf(-v0));
        v1 = 1.f / (1.f + __expf(-v1));
        float2 fv = {v0, v1};
        *(float2*)&ms[(u32)(lbase + (int)oo)*202u + pp*2u] = fv;
      }
    }
  }
  {                                                // x channels [527,1551): float4 loads
    int xs_ = cc0 > 527 ? cc0 : 527;
    int xe = cc0 + 32 < 1551 ? cc0 + 32 : 1551;
    if (xs_ < xe){
      int nx = xe - xs_, lbase = xs_ - cc0, cxs = xs_ - 527;
      const float4* xg = (const float4*)(x + ((size_t)b*1024 + cxs)*196);
      for (int i = tid; i < nx*49; i += 256){
        float4 v = xg[i];
        u32 c = (u32)i / 49u, p4 = (u32)i - c*49u;
        float* dst = &ms[(u32)(lbase + (int)c)*202u + p4*4u];
        float2 lo = {v.x, v.y}, hi = {v.z, v.w};
        *(float2*)dst = lo;
        *(float2*)(dst + 2) = hi;
      }
    }
  }
  {                                                // K pad [1551,1600) -> zeros
    int ps = cc0 > 1551 ? cc0 : 1551;
    int pe = cc0 + 32;
    if (ps < pe){
      int np = pe - ps, lbase = ps - cc0;
      for (int i = tid; i < np*196; i += 256){
        u32 c = (u32)i / 196u, p = (u32)i - c*196u;
        ms[(u32)(lbase + (int)c)*202u + p] = 0.f;
      }
    }
  }
  __syncthreads();

  for (int t = tid; t < 448; t += 256){            // conv: one thread = one (cc, out-row)
    int cc = t & 31, i = t >> 5;
    float wr[9];
    #pragma unroll
    for (int qq = 0; qq < 9; ++qq) wr[qq] = wd[cc][qq];
    float topm = (i > 0) ? 1.f : 0.f, botm = (i < 13) ? 1.f : 0.f;
    wr[0] *= topm; wr[1] *= topm; wr[2] *= topm;
    wr[6] *= botm; wr[7] *= botm; wr[8] *= botm;
    float bb = bd[cc];
    float rr[3][16];
    #pragma unroll
    for (int d = 0; d < 3; ++d){
      rr[d][0] = 0.f; rr[d][15] = 0.f;
      int rowr = i + d - 1;
      rowr = rowr < 0 ? 0 : (rowr > 13 ? 13 : rowr);
      const float* src = &ms[cc*202 + rowr*14];
      #pragma unroll
      for (int j = 0; j < 7; ++j)
        *(float2*)&rr[d][1 + 2*j] = *(const float2*)&src[2*j];
    }
    size_t obase = ((size_t)b*196 + i*14) * 1600 + cc0 + cc;
    #pragma unroll
    for (int k = 0; k < 14; ++k){
      float a = bb;
      #pragma unroll
      for (int dy = 0; dy < 3; ++dy)
        #pragma unroll
        for (int dx = 0; dx < 3; ++dx)
          a += wr[dy*3+dx] * rr[dy][k + dx];
      Adw[obase + (size_t)k*1600] = f2bf(a);
    }
  }
}

// ---------------- NT GEMM (r6 structure + XCD swizzle): 128x128 tile, BK=64, 256 thr ----
// 1D grid 1568 = 392 m-blocks x 4 n-blocks; lin=(g&7)*196+(g>>3) gives each XCD a
// contiguous strip of 49 m-blocks x all 4 n-blocks -> A-tile + B stay hot in its L2.
// MODE 0: store bf16 transposed zT[n][m]. MODE 1: store f32 NCHW-transposed (o).
template<int MODE>
__global__ __launch_bounds__(256,3) void gemm_kernel(
    const u16* __restrict__ A, const u16* __restrict__ Bw,
    const float* __restrict__ bias, void* __restrict__ outp,
    float* __restrict__ stats, int K){
  __shared__ __align__(16) char smem[33280];
  u16* As = (u16*)smem;            // [128][64] bf16, XOR-swizzled in 8-elt groups
  u16* Bs = (u16*)(smem + 16384);

  int tid = threadIdx.x;
  int w = tid >> 6, l = tid & 63;
  int wm = w >> 1, wn = w & 1;
  int lr = l & 15, lq = l >> 4;
  u32 g = blockIdx.x;
  u32 lin = (g & 7u) * 196u + (g >> 3);
  int n0 = (int)(lin & 3u) * 128;
  int m0 = (int)(lin >> 2) * 128;

  f32x4 acc[4][4] = {};
  int kTiles = K >> 6;

  for (int kt = 0; kt < kTiles; ++kt){
    if (kt) __syncthreads();               // previous tile's readers done
    #pragma unroll
    for (int i = 0; i < 4; ++i){
      int s = tid + i*256;
      int row = s >> 3, c8 = s & 7, sc = c8 ^ (row & 7);
      GLDS16(A  + (size_t)(m0 + row)*K + kt*64 + sc*8, As + s*8);
      GLDS16(Bw + (size_t)(n0 + row)*K + kt*64 + sc*8, Bs + s*8);
    }
    __syncthreads();                       // drains vmcnt -> LDS tile ready
    #pragma unroll
    for (int ks = 0; ks < 2; ++ks){
      bf16x8 af[4], bfv[4];
      #pragma unroll
      for (int mi = 0; mi < 4; ++mi){
        int row = wm*64 + mi*16 + lr;
        int q = (ks*4 + lq) ^ (row & 7);
        af[mi] = *(const bf16x8*)(As + row*64 + q*8);
      }
      #pragma unroll
      for (int ni = 0; ni < 4; ++ni){
        int row = wn*64 + ni*16 + lr;
        int q = (ks*4 + lq) ^ (row & 7);
        bfv[ni] = *(const bf16x8*)(Bs + row*64 + q*8);
      }
      #pragma unroll
      for (int mi = 0; mi < 4; ++mi)
        #pragma unroll
        for (int ni = 0; ni < 4; ++ni)
          acc[mi][ni] = __builtin_amdgcn_mfma_f32_16x16x32_bf16(af[mi], bfv[ni], acc[mi][ni], 0, 0, 0);
    }
  }

  // bias + per-column BN stats (sum, sumsq)
  #pragma unroll
  for (int ni = 0; ni < 4; ++ni){
    int col = n0 + wn*64 + ni*16 + lr;
    float bb = bias[col];
    float s1 = 0.f, s2 = 0.f;
    #pragma unroll
    for (int mi = 0; mi < 4; ++mi)
      #pragma unroll
      for (int r = 0; r < 4; ++r){
        float v = acc[mi][ni][r] + bb;
        acc[mi][ni][r] = v;
        s1 += v; s2 += v*v;
      }
    s1 += __shfl_xor(s1, 16); s1 += __shfl_xor(s1, 32);
    s2 += __shfl_xor(s2, 16); s2 += __shfl_xor(s2, 32);
    if (lq == 0){
      atomicAdd(&stats[col], s1);
      atomicAdd(&stats[512 + col], s2);
    }
  }

  // both modes: LDS transpose so stores are m-contiguous
  __syncthreads();                         // all waves done reading As/Bs
  float* eb = (float*)smem;                // 2 x [64][65] f32
  #pragma unroll
  for (int rnd = 0; rnd < 2; ++rnd){
    if (wm == rnd){
      float* e = eb + wn * (64*65);
      #pragma unroll
      for (int mi = 0; mi < 4; ++mi)
        #pragma unroll
        for (int ni = 0; ni < 4; ++ni)
          #pragma unroll
          for (int r = 0; r < 4; ++r)
            e[(mi*16 + lq*4 + r)*65 + ni*16 + lr] = acc[mi][ni][r];
      int m = m0 + wm*64 + l;              // same-wave readback (DS in-order per wave)
      if (MODE == 0){
        u16* ob = (u16*)outp + (size_t)(n0 + wn*64)*50176 + m;
        #pragma unroll 8
        for (int no = 0; no < 64; ++no)
          ob[(size_t)no*50176] = f2bf(e[l*65 + no]);
      } else {
        u32 bq = (u32)m / 196u;
        u32 ij = (u32)m - bq*196u;
        float* ob = (float*)outp + ((size_t)bq*512 + n0 + wn*64)*196 + ij;
        #pragma unroll 8
        for (int no = 0; no < 64; ++no)
          ob[(size_t)no*196] = e[l*65 + no];
      }
    }
    __syncthreads();
  }
}

// ---------------- BN prep: stats -> scale/shift ----------------
__global__ void bnprep_kernel(const float* __restrict__ stats, const float* __restrict__ gamma,
    const float* __restrict__ beta, float* __restrict__ sc, float* __restrict__ sh){
  int o = threadIdx.x;
  float m = stats[o] * (1.f/50176.f);
  float v = stats[512+o] * (1.f/50176.f) - m*m;
  float inv = rsqrtf(v + EPSBN);
  float g = gamma[o] * inv;
  sc[o] = g;
  sh[o] = beta[o] - m*g;
}

// ---------------- final: relu(bn(o)) in place on d_out (NCHW) ----------------
__global__ void final_kernel(float4* __restrict__ o4, const float* __restrict__ sc,
                             const float* __restrict__ sh){
  u32 stride = gridDim.x * blockDim.x;
  for (u32 i = blockIdx.x*blockDim.x + threadIdx.x; i < 6422528u; i += stride){
    u32 oc = (i / 49u) & 511u;
    float s = sc[oc], t = sh[oc];
    float4 v = o4[i];
    v.x = fmaxf(fmaf(v.x, s, t), 0.f);
    v.y = fmaxf(fmaf(v.y, s, t), 0.f);
    v.z = fmaxf(fmaf(v.z, s, t), 0.f);
    v.w = fmaxf(fmaf(v.w, s, t), 0.f);
    o4[i] = v;
  }
}

extern "C" void kernel_launch(void* const* d_in, const int* in_sizes, int n_in,
                              void* d_out, int out_size, void* d_ws, size_t ws_size,
                              hipStream_t stream){
  (void)in_sizes; (void)n_in; (void)out_size; (void)ws_size;
  const float* y      = (const float*)d_in[0];
  const float* x      = (const float*)d_in[1];
  const float* fc1    = (const float*)d_in[2];
  const float* fc2    = (const float*)d_in[3];
  const float* convw  = (const float*)d_in[4];
  const float* convb  = (const float*)d_in[5];
  const float* dconvw = (const float*)d_in[6];
  const float* dconvb = (const float*)d_in[7];
  const float* dw1w   = (const float*)d_in[8];
  const float* dw1b   = (const float*)d_in[9];
  const float* pw1w   = (const float*)d_in[10];
  const float* pw1b   = (const float*)d_in[11];
  const float* gamma  = (const float*)d_in[12];
  const float* beta   = (const float*)d_in[13];

  char* ws = (char*)d_ws;
  u16* covT   = (u16*)(ws + OFF_COVT);
  u16* Adw    = (u16*)(ws + OFF_ADW);
  float* sse  = (float*)(ws + OFF_S);
  u16* wbz    = (u16*)(ws + OFF_WBZ);
  u16* wbp    = (u16*)(ws + OFF_WBP);
  float* statsZ = (float*)(ws + OFF_STATSZ);
  float* statsO = (float*)(ws + OFF_STATSO);
  float* scz  = (float*)(ws + OFF_SCZ);
  float* shz  = (float*)(ws + OFF_SHZ);
  float* sco  = (float*)(ws + OFF_SCO);
  float* sho  = (float*)(ws + OFF_SHO);
  u16* zT     = (u16*)d_out;      // z transposed [512][50176] bf16 in d_out, dead before o written
  float* outf = (float*)d_out;

  hipMemsetAsync(statsZ, 0, 8192, stream);
  se_kernel<<<256, 64, 0, stream>>>(y, fc1, fc2, sse);
  wconv_kernel<<<2048, 256, 0, stream>>>(convw, pw1w, wbz, wbp);
  cov_kernel<<<dim3(64, 256), 256, 0, stream>>>(x, dconvw, dconvb, covT);
  gemm_kernel<0><<<1568, 256, 0, stream>>>(covT, wbz, convb, (void*)zT, statsZ, 1024);
  bnprep_kernel<<<1, 512, 0, stream>>>(statsZ, gamma, beta, scz, shz);
  adw_kernel<<<dim3(50, 256), 256, 0, stream>>>(y, sse, zT, scz, shz, x, dw1w, dw1b, Adw);
  gemm_kernel<1><<<1568, 256, 0, stream>>>(Adw, wbp, pw1b, (void*)outf, statsO, 1600);
  bnprep_kernel<<<1, 512, 0, stream>>>(statsO, gamma, beta, sco, sho);
  final_kernel<<<8192, 256, 0, stream>>>((float4*)outf, sco, sho);
}